// Round 10
// baseline (1042.621 us; speedup 1.0000x reference)
//
#include <hip/hip_runtime.h>
#include <hip/hip_bf16.h>

typedef __attribute__((ext_vector_type(8))) short bfrag_t;   // 8 bf16 (4 VGPRs)
typedef __attribute__((ext_vector_type(4))) float accum_t;   // 4 f32
typedef __attribute__((ext_vector_type(8))) unsigned short us8_t;

static_assert(sizeof(bfrag_t) == 16, "frag size");

static constexpr int M_NODES = 50000;
static constexpr int E_EDGES = 156000;
static constexpr int MT      = (M_NODES + 127) / 128;  // 391 M-tiles

// ---- manual RNE f32 -> bf16 ----
__device__ __forceinline__ unsigned short f2bf(float f) {
  unsigned int u = __float_as_uint(f);
  u = (u + 0x7FFFu + ((u >> 16) & 1u)) >> 16;
  return (unsigned short)u;
}
__device__ __forceinline__ float bf2f(unsigned short u) {
  return __uint_as_float(((unsigned int)u) << 16);
}

__device__ __forceinline__ void gll16(const unsigned short* g, unsigned short* l) {
  __builtin_amdgcn_global_load_lds(
      (const __attribute__((address_space(1))) void*)g,
      (__attribute__((address_space(3))) void*)l,
      16, 0, 0);
}

// ---- packed bf16x2 atomic add (HW instruction if available, CAS fallback) ----
typedef __attribute__((ext_vector_type(2))) short s2v;
__device__ __forceinline__ void agg_atomic_add(unsigned int* p, unsigned int zv) {
#if __has_builtin(__builtin_amdgcn_global_atomic_fadd_v2bf16)
  s2v v;
  __builtin_memcpy(&v, &zv, 4);
  __builtin_amdgcn_global_atomic_fadd_v2bf16(
      (__attribute__((address_space(1))) s2v*)p, v);
#else
  unsigned int old = *p, assumed;
  do {
    assumed = old;
    float lo = bf2f((unsigned short)(assumed & 0xffffu)) +
               bf2f((unsigned short)(zv & 0xffffu));
    float hi = bf2f((unsigned short)(assumed >> 16)) +
               bf2f((unsigned short)(zv >> 16));
    unsigned int nv = (unsigned int)f2bf(lo) | ((unsigned int)f2bf(hi) << 16);
    old = atomicCAS(p, assumed, nv);
  } while (old != assumed);
#endif
}

// ---- weight prep (R7-validated) ----
__global__ void cast_w_kernel(const float* __restrict__ Wself,
                              const float* __restrict__ W1,
                              const float* __restrict__ W2,
                              const float* __restrict__ b2,
                              unsigned short* __restrict__ Wt1,
                              unsigned short* __restrict__ Wt2,
                              float* __restrict__ bias2) {
  int idx = blockIdx.x * 256 + threadIdx.x;
  if (idx < 1048576) {                       // Wt1
    int n = idx >> 9, k = idx & 511;
    float v = (n < 512)
        ? Wself[k * 512 + n]
        : W1[(size_t)((n - 512) >> 9) * 262144 + k * 512 + ((n - 512) & 511)];
    Wt1[idx] = f2bf(v);
  } else if (idx < 1835008) {                // Wt2 (j = n*1536 + kk)
    int j = idx - 1048576;
    int kk = j % 1536;
    int n  = j / 1536;
    Wt2[j] = f2bf(W2[(size_t)(kk >> 9) * 262144 + (size_t)(kk & 511) * 512 + n]);
  } else if (idx < 1835520) {                // bias2
    int c = idx - 1835008;
    bias2[c] = b2[c] + b2[512 + c] + b2[1024 + c];
  }
}

// ---- cast x (f32) -> xb (bf16), vectorized ----
__global__ void cast_x_kernel(const float* __restrict__ x,
                              unsigned short* __restrict__ xb, int n) {
  int stride = gridDim.x * blockDim.x;
  int n4 = n >> 2;
  for (int i = blockIdx.x * blockDim.x + threadIdx.x; i < n4; i += stride) {
    float4 v = ((const float4*)x)[i];
    ushort4 u;
    u.x = f2bf(v.x); u.y = f2bf(v.y); u.z = f2bf(v.z); u.w = f2bf(v.w);
    ((ushort4*)xb)[i] = u;
  }
}

// ---- fused scatter, all relations, packed bf16 atomics (R8-validated) ----
__global__ void scatter_all_kernel(const unsigned short* __restrict__ Z,
                                   const int* __restrict__ ei,
                                   const int* __restrict__ et,
                                   unsigned short* __restrict__ agg) {
  int e    = blockIdx.x * 4 + (threadIdx.x >> 6);
  int lane = threadIdx.x & 63;
  if (e >= E_EDGES) return;
  int rel = et[e];
  int src = ei[e];
  int dst = ei[E_EDGES + e];
  const unsigned int* zs = (const unsigned int*)(Z + (size_t)src * 1536 + rel * 512);
  unsigned int* ad = (unsigned int*)(agg + (size_t)dst * 1536 + rel * 512);
  unsigned int v[4];
#pragma unroll
  for (int j = 0; j < 4; ++j) v[j] = zs[j * 64 + lane];
#pragma unroll
  for (int j = 0; j < 4; ++j) agg_atomic_add(ad + j * 64 + lane, v[j]);
}

// ---- fused relu, in place over Z: Z = relu(Z + agg + b1[col]) ----
__global__ void relu_all_kernel(unsigned short* __restrict__ Z,
                                const unsigned short* __restrict__ agg,
                                const float* __restrict__ b1) {  // [1536] flat
  int i = blockIdx.x * 256 + threadIdx.x;   // one thread = 8 cols
  if (i >= M_NODES * 192) return;
  int c = (i % 192) * 8;
  us8_t z = ((const us8_t*)Z)[i];
  us8_t a = ((const us8_t*)agg)[i];
  us8_t o;
#pragma unroll
  for (int j = 0; j < 8; ++j) {
    float v = bf2f((unsigned short)z[j]) + bf2f((unsigned short)a[j]) + b1[c + j];
    o[j] = f2bf(fmaxf(v, 0.f));
  }
  ((us8_t*)Z)[i] = o;
}

// ======== multi-N-tile GEMM: R7-proven 128^2 inner loop, NTPB tiles/block ====
// Amortizes the measured ~25 us per-block fixed cost over NTPB K-loops.
// MODE 1: col<512 -> f32 out + bias; col>=512 -> bf16 Z at col-512 (no bias).
// MODE 2: f32 RMW accumulate + bias.
template <int NGRP, int NTPB, int MODE>
__global__ __launch_bounds__(256) void gemmml_kernel(
    const unsigned short* __restrict__ A,
    const unsigned short* __restrict__ Bt,
    int K,
    float* __restrict__ outF,
    unsigned short* __restrict__ outB,
    const float* __restrict__ biasF) {
  __shared__ alignas(16) unsigned short As[2][4096];  // [buf][kc][row][8]
  __shared__ alignas(16) unsigned short Bs[2][4096];
  const int tid  = threadIdx.x;
  const int lane = tid & 63;
  const int wid  = tid >> 6;
  const int wr   = wid >> 1;
  const int wc   = wid & 1;

  // T1: bijective XCD-chunked swizzle (m204 general form).
  constexpr int nwg = MT * NGRP;
  constexpr int q   = nwg / 8;
  constexpr int rr  = nwg % 8;
  const int orig = blockIdx.x;
  const int xcd  = orig & 7;
  const int lid  = orig >> 3;
  const int swz  = (xcd < rr ? xcd * (q + 1) : rr * (q + 1) + (xcd - rr) * q) + lid;
  const int tileM  = (swz / NGRP) * 128;
  const int tileNb = (swz % NGRP) * (NTPB * 128);

  const int t0 = tid, t1 = tid + 256;
  const int kc0 = t0 >> 7, r0 = t0 & 127;
  const int kc1 = t1 >> 7, r1 = t1 & 127;
  int ar0 = tileM + r0; ar0 = ar0 < M_NODES ? ar0 : M_NODES - 1;
  int ar1 = tileM + r1; ar1 = ar1 < M_NODES ? ar1 : M_NODES - 1;
  const unsigned short* gA0 = A + (size_t)ar0 * K + kc0 * 8;
  const unsigned short* gA1 = A + (size_t)ar1 * K + kc1 * 8;

  const int kcl = lane >> 4;
  const int fr  = lane & 15;
  const unsigned short* pAf = &As[0][kcl * 1024 + (wr * 64 + fr) * 8];
  const unsigned short* pBf = &Bs[0][kcl * 1024 + (wc * 64 + fr) * 8];
  const int rq = lane >> 4;
  const int ksteps = K >> 5;

  for (int nt = 0; nt < NTPB; ++nt) {
    const int tileN = tileNb + nt * 128;
    const unsigned short* gB0 = Bt + (size_t)(tileN + r0) * K + kc0 * 8;
    const unsigned short* gB1 = Bt + (size_t)(tileN + r1) * K + kc1 * 8;

    accum_t acc[4][4] = {};

#define STAGE(b, ks)                                  \
  do {                                                \
    const int koff_ = (ks) * 32;                      \
    gll16(gA0 + koff_, &As[(b)][t0 * 8]);             \
    gll16(gA1 + koff_, &As[(b)][t1 * 8]);             \
    gll16(gB0 + koff_, &Bs[(b)][t0 * 8]);             \
    gll16(gB1 + koff_, &Bs[(b)][t1 * 8]);             \
  } while (0)

    STAGE(0, 0);
    for (int ks = 0; ks < ksteps; ++ks) {
      const int cur = ks & 1;
      if (ks + 1 < ksteps) {
        STAGE(cur ^ 1, ks + 1);                           // prefetch next
        asm volatile("s_waitcnt vmcnt(4)" ::: "memory");  // wait current only
      } else {
        asm volatile("s_waitcnt vmcnt(0)" ::: "memory");
      }
      __builtin_amdgcn_s_barrier();

      bfrag_t a[4], b[4];
      const unsigned short* pA = pAf + cur * 4096;
      const unsigned short* pB = pBf + cur * 4096;
#pragma unroll
      for (int m = 0; m < 4; ++m) a[m] = *(const bfrag_t*)(pA + m * 16 * 8);
#pragma unroll
      for (int n = 0; n < 4; ++n) b[n] = *(const bfrag_t*)(pB + n * 16 * 8);
      __builtin_amdgcn_s_setprio(1);
#pragma unroll
      for (int m = 0; m < 4; ++m)
#pragma unroll
        for (int n = 0; n < 4; ++n)
          acc[m][n] = __builtin_amdgcn_mfma_f32_16x16x32_bf16(a[m], b[n], acc[m][n], 0, 0, 0);
      __builtin_amdgcn_s_setprio(0);
      __builtin_amdgcn_s_barrier();
    }
#undef STAGE

    // epilogue: C row = (lane>>4)*4 + p, col = lane&15 (m89-verified layout)
#pragma unroll
    for (int n = 0; n < 4; ++n) {
      const int col = tileN + wc * 64 + n * 16 + fr;
      const float bv = (MODE == 2 || col < 512) ? biasF[col & 511] : 0.f;
#pragma unroll
      for (int m = 0; m < 4; ++m) {
        const int rbase = tileM + wr * 64 + m * 16 + rq * 4;
#pragma unroll
        for (int p = 0; p < 4; ++p) {
          const int row = rbase + p;
          if (row < M_NODES) {
            float v = acc[m][n][p] + bv;
            if (MODE == 1) {
              if (col < 512) outF[(size_t)row * 512 + col] = v;
              else           outB[(size_t)row * 1536 + (col - 512)] = f2bf(v);
            } else {
              outF[(size_t)row * 512 + col] += v;
            }
          }
        }
      }
    }
  }
}

extern "C" void kernel_launch(void* const* d_in, const int* in_sizes, int n_in,
                              void* d_out, int out_size, void* d_ws, size_t ws_size,
                              hipStream_t stream) {
  const float* x     = (const float*)d_in[0];
  const int*   ei    = (const int*)d_in[1];
  const int*   et    = (const int*)d_in[2];
  const float* Wself = (const float*)d_in[3];
  const float* bself = (const float*)d_in[4];
  const float* W1    = (const float*)d_in[5];
  const float* b1    = (const float*)d_in[6];
  const float* W2    = (const float*)d_in[7];
  const float* b2    = (const float*)d_in[8];
  float* out = (float*)d_out;

  // ws layout (310.9 MB, R7/R8/R9-proven footprint):
  //   [0, 153.6 MB): agg bf16 [M,1536] -- hosts xb bf16 [M,512] during GEMM-1
  //   [153.6, 307.2 MB): Z bf16 [M,1536]
  //   [307.2 MB +): Wt1, Wt2, bias2
  char* ws = (char*)d_ws;
  unsigned short* xb    = (unsigned short*)ws;
  unsigned short* agg   = (unsigned short*)ws;
  unsigned short* Z     = (unsigned short*)(ws + 153600000);
  unsigned short* Wt1   = (unsigned short*)(ws + 307200000);   // 2.1 MB
  unsigned short* Wt2   = (unsigned short*)(ws + 309297152);   // 1.6 MB
  float*          bias2 = (float*)(ws + 310870016);            // 2 KB

  cast_w_kernel<<<7171, 256, 0, stream>>>(Wself, W1, W2, b2, Wt1, Wt2, bias2);
  cast_x_kernel<<<2048, 256, 0, stream>>>(x, xb, M_NODES * 512);

  // G1: Y = x @ [W_self | W1_0 | W1_1 | W1_2]  (M=50000, N=2048, K=512)
  // 782 blocks, each does 8 N-tiles (128 virtual K-steps).
  gemmml_kernel<2, 8, 1><<<MT * 2, 256, 0, stream>>>(xb, Wt1, 512, out, Z, bself);

  hipMemsetAsync(agg, 0, (size_t)M_NODES * 1536 * sizeof(unsigned short), stream);
  scatter_all_kernel<<<E_EDGES / 4, 256, 0, stream>>>(Z, ei, et, agg);
  relu_all_kernel<<<(M_NODES * 192 + 255) / 256, 256, 0, stream>>>(Z, agg, b1);

  // G2: out += [h0|h1|h2] @ [W2_0; W2_1; W2_2] + bias2  (N=512, K=1536)
  // 782 blocks, each does 2 N-tiles (96 virtual K-steps).
  gemmml_kernel<2, 2, 2><<<MT * 2, 256, 0, stream>>>(Z, Wt2, 1536, out, nullptr, bias2);
}

// Round 11
// 785.861 us; speedup vs baseline: 1.3267x; 1.3267x over previous
//
#include <hip/hip_runtime.h>
#include <hip/hip_bf16.h>

typedef __attribute__((ext_vector_type(8))) short bfrag_t;   // 8 bf16 (4 VGPRs)
typedef __attribute__((ext_vector_type(4))) float accum_t;   // 4 f32
typedef __attribute__((ext_vector_type(8))) unsigned short us8_t;

static_assert(sizeof(bfrag_t) == 16, "frag size");

static constexpr int M_NODES = 50000;
static constexpr int E_EDGES = 156000;
static constexpr int MT256   = (M_NODES + 255) / 256;  // 196 M-tiles

// ---- manual RNE f32 -> bf16 ----
__device__ __forceinline__ unsigned short f2bf(float f) {
  unsigned int u = __float_as_uint(f);
  u = (u + 0x7FFFu + ((u >> 16) & 1u)) >> 16;
  return (unsigned short)u;
}
__device__ __forceinline__ float bf2f(unsigned short u) {
  return __uint_as_float(((unsigned int)u) << 16);
}

__device__ __forceinline__ void gll16(const unsigned short* g, unsigned short* l) {
  __builtin_amdgcn_global_load_lds(
      (const __attribute__((address_space(1))) void*)g,
      (__attribute__((address_space(3))) void*)l,
      16, 0, 0);
}

// ---- packed bf16x2 atomic add (HW instruction if available, CAS fallback) ----
typedef __attribute__((ext_vector_type(2))) short s2v;
__device__ __forceinline__ void agg_atomic_add(unsigned int* p, unsigned int zv) {
#if __has_builtin(__builtin_amdgcn_global_atomic_fadd_v2bf16)
  s2v v;
  __builtin_memcpy(&v, &zv, 4);
  __builtin_amdgcn_global_atomic_fadd_v2bf16(
      (__attribute__((address_space(1))) s2v*)p, v);
#else
  unsigned int old = *p, assumed;
  do {
    assumed = old;
    float lo = bf2f((unsigned short)(assumed & 0xffffu)) +
               bf2f((unsigned short)(zv & 0xffffu));
    float hi = bf2f((unsigned short)(assumed >> 16)) +
               bf2f((unsigned short)(zv >> 16));
    unsigned int nv = (unsigned int)f2bf(lo) | ((unsigned int)f2bf(hi) << 16);
    old = atomicCAS(p, assumed, nv);
  } while (old != assumed);
#endif
}

// ---- weight prep (R7-validated) ----
__global__ void cast_w_kernel(const float* __restrict__ Wself,
                              const float* __restrict__ W1,
                              const float* __restrict__ W2,
                              const float* __restrict__ b2,
                              unsigned short* __restrict__ Wt1,
                              unsigned short* __restrict__ Wt2,
                              float* __restrict__ bias2) {
  int idx = blockIdx.x * 256 + threadIdx.x;
  if (idx < 1048576) {                       // Wt1
    int n = idx >> 9, k = idx & 511;
    float v = (n < 512)
        ? Wself[k * 512 + n]
        : W1[(size_t)((n - 512) >> 9) * 262144 + k * 512 + ((n - 512) & 511)];
    Wt1[idx] = f2bf(v);
  } else if (idx < 1835008) {                // Wt2 (j = n*1536 + kk)
    int j = idx - 1048576;
    int kk = j % 1536;
    int n  = j / 1536;
    Wt2[j] = f2bf(W2[(size_t)(kk >> 9) * 262144 + (size_t)(kk & 511) * 512 + n]);
  } else if (idx < 1835520) {                // bias2
    int c = idx - 1835008;
    bias2[c] = b2[c] + b2[512 + c] + b2[1024 + c];
  }
}

// ---- cast x (f32) -> xb (bf16), vectorized ----
__global__ void cast_x_kernel(const float* __restrict__ x,
                              unsigned short* __restrict__ xb, int n) {
  int stride = gridDim.x * blockDim.x;
  int n4 = n >> 2;
  for (int i = blockIdx.x * blockDim.x + threadIdx.x; i < n4; i += stride) {
    float4 v = ((const float4*)x)[i];
    ushort4 u;
    u.x = f2bf(v.x); u.y = f2bf(v.y); u.z = f2bf(v.z); u.w = f2bf(v.w);
    ((ushort4*)xb)[i] = u;
  }
}

// ---- fused scatter, all relations, packed bf16 atomics (R8-validated) ----
__global__ void scatter_all_kernel(const unsigned short* __restrict__ Z,
                                   const int* __restrict__ ei,
                                   const int* __restrict__ et,
                                   unsigned short* __restrict__ agg) {
  int e    = blockIdx.x * 4 + (threadIdx.x >> 6);
  int lane = threadIdx.x & 63;
  if (e >= E_EDGES) return;
  int rel = et[e];
  int src = ei[e];
  int dst = ei[E_EDGES + e];
  const unsigned int* zs = (const unsigned int*)(Z + (size_t)src * 1536 + rel * 512);
  unsigned int* ad = (unsigned int*)(agg + (size_t)dst * 1536 + rel * 512);
  unsigned int v[4];
#pragma unroll
  for (int j = 0; j < 4; ++j) v[j] = zs[j * 64 + lane];
#pragma unroll
  for (int j = 0; j < 4; ++j) agg_atomic_add(ad + j * 64 + lane, v[j]);
}

// ---- fused relu, in place over Z: Z = relu(Z + agg + b1[col]) ----
__global__ void relu_all_kernel(unsigned short* __restrict__ Z,
                                const unsigned short* __restrict__ agg,
                                const float* __restrict__ b1) {  // [1536] flat
  int i = blockIdx.x * 256 + threadIdx.x;   // one thread = 8 cols
  if (i >= M_NODES * 192) return;
  int c = (i % 192) * 8;
  us8_t z = ((const us8_t*)Z)[i];
  us8_t a = ((const us8_t*)agg)[i];
  us8_t o;
#pragma unroll
  for (int j = 0; j < 8; ++j) {
    float v = bf2f((unsigned short)z[j]) + bf2f((unsigned short)a[j]) + b1[c + j];
    o[j] = f2bf(fmaxf(v, 0.f));
  }
  ((us8_t*)Z)[i] = o;
}

// ====== 8-wave 256x128 GEMM, BK=32, 3-buf ring, 2 blocks/CU (72KB LDS) ======
// Per K-tile: {vmcnt(3); barrier; 8 ds_read_b128; stage kt+2 (3 gll16, depth-2,
// into the buffer last read at kt-1 -> race-safe); setprio; 16 MFMA}.
// MODE 1: tileN<512 -> f32 out + bself; tileN>=512 -> bf16 Z tile stored via
//         LDS repack as full-sector 128B-contiguous us8 stores (no bias).
// MODE 2: f32 RMW accumulate + bias.
template <int NTC, int MODE, int KTOT>
__global__ __launch_bounds__(512, 4) void gemm2b_kernel(
    const unsigned short* __restrict__ A,
    const unsigned short* __restrict__ Bt,
    float* __restrict__ outF,
    unsigned short* __restrict__ outB,
    const float* __restrict__ biasF) {
  constexpr int NT = KTOT / 32;
  // buf (u16): A [kc(4)][row(256)][8] at 0..8191, B [kc(4)][col(128)][8] at 8192..12287
  __shared__ alignas(16) unsigned short L[3][12288];  // 72 KB
  const int tid  = threadIdx.x;
  const int lane = tid & 63;
  const int wid  = tid >> 6;   // 0..7
  const int wr   = wid >> 1;   // 0..3 : 64-row band within 256
  const int wn   = wid & 1;    // 0..1 : 64-col band within 128
  const int fr   = lane & 15;
  const int kcl  = lane >> 4;

  // T1: XCD-chunked swizzle (nwg % 8 == 0 for both instantiations)
  constexpr int nwg = MT256 * NTC;
  constexpr int q   = nwg / 8;
  const int orig = blockIdx.x;
  const int swz  = (orig & 7) * q + (orig >> 3);
  const int tileM = (swz / NTC) * 256;
  const int tileN = (swz % NTC) * 128;

  accum_t acc[4][4] = {};

  // staging: thread covers A slots {tid, tid+512} and B slot {tid}
  const int rowS = tid & 255;
  int arow = tileM + rowS; arow = arow < M_NODES ? arow : M_NODES - 1;
  const unsigned short* gA = A  + (size_t)arow * KTOT + (tid >> 8) * 8;
  const unsigned short* gB = Bt + (size_t)(tileN + (tid & 127)) * KTOT + (tid >> 7) * 8;

#define STG(buf, kt) do {                                 \
    gll16(gA + (kt) * 32,      &L[buf][tid * 8]);         \
    gll16(gA + (kt) * 32 + 16, &L[buf][tid * 8 + 4096]);  \
    gll16(gB + (kt) * 32,      &L[buf][8192 + tid * 8]);  \
  } while (0)

  // fragment read offsets (u16 within buf)
  const int aoff = kcl * 2048 + (wr * 64 + fr) * 8;          // + mf*128
  const int boff = 8192 + kcl * 1024 + (wn * 64 + fr) * 8;   // + nf*128

  STG(0, 0); STG(1, 1);   // depth-2 prologue

  for (int kt = 0; kt < NT; ++kt) {
    if (kt + 1 < NT) asm volatile("s_waitcnt vmcnt(3)" ::: "memory");  // kt landed
    else             asm volatile("s_waitcnt vmcnt(0)" ::: "memory");
    __builtin_amdgcn_s_barrier();

    const unsigned short* Ls = &L[kt % 3][0];
    bfrag_t b[4], a[4];
#pragma unroll
    for (int nf = 0; nf < 4; ++nf)
      b[nf] = *(const bfrag_t*)(Ls + boff + nf * 128);
#pragma unroll
    for (int mf = 0; mf < 4; ++mf)
      a[mf] = *(const bfrag_t*)(Ls + aoff + mf * 128);
    if (kt + 2 < NT) STG((kt + 2) % 3, kt + 2);  // buffer last read at kt-1: safe
    __builtin_amdgcn_s_setprio(1);
#pragma unroll
    for (int mf = 0; mf < 4; ++mf)
#pragma unroll
      for (int nf = 0; nf < 4; ++nf)
        acc[mf][nf] = __builtin_amdgcn_mfma_f32_16x16x32_bf16(a[mf], b[nf], acc[mf][nf], 0, 0, 0);
    __builtin_amdgcn_s_setprio(0);
  }
#undef STG

  __syncthreads();   // K-loop LDS reads done chip... CU-wide; L reusable as scratch

  const int rq = lane >> 4;
  if (MODE == 1 && tileN >= 512) {
    // bf16 Z tile: repack through LDS (stride 72 u16, 16B-aligned rows),
    // then 8-rows x 128B contiguous stores -> full sectors.
    unsigned short* Wld = &L[0][0] + wid * 4608;   // 64 x 72 u16, wave-private
#pragma unroll
    for (int mf = 0; mf < 4; ++mf)
#pragma unroll
      for (int nf = 0; nf < 4; ++nf)
#pragma unroll
        for (int p = 0; p < 4; ++p)
          Wld[(mf * 16 + rq * 4 + p) * 72 + nf * 16 + fr] = f2bf(acc[mf][nf][p]);
    const int r8 = lane >> 3;   // row within 8-row pass
    const int ch = lane & 7;    // 16B chunk within 128B row
    const size_t zc = (size_t)(tileN - 512) + wn * 64 + ch * 8;
#pragma unroll
    for (int pass = 0; pass < 8; ++pass) {
      const int lrow = pass * 8 + r8;
      const int grow = tileM + wr * 64 + lrow;
      us8_t v = *(const us8_t*)&Wld[lrow * 72 + ch * 8];
      if (grow < M_NODES)
        *(us8_t*)&outB[(size_t)grow * 1536 + zc] = v;
    }
  } else {
    // f32 paths: 64B segments per store group, already full-sector
#pragma unroll
    for (int nf = 0; nf < 4; ++nf) {
      const int col = tileN + wn * 64 + nf * 16 + fr;
      const float bv = biasF[col & 511];
#pragma unroll
      for (int mf = 0; mf < 4; ++mf) {
        const int rbase = tileM + wr * 64 + mf * 16 + rq * 4;
#pragma unroll
        for (int p = 0; p < 4; ++p) {
          const int row = rbase + p;
          if (row < M_NODES) {
            float v = acc[mf][nf][p] + bv;
            if (MODE == 1) outF[(size_t)row * 512 + col] = v;
            else           outF[(size_t)row * 512 + col] += v;
          }
        }
      }
    }
  }
}

extern "C" void kernel_launch(void* const* d_in, const int* in_sizes, int n_in,
                              void* d_out, int out_size, void* d_ws, size_t ws_size,
                              hipStream_t stream) {
  const float* x     = (const float*)d_in[0];
  const int*   ei    = (const int*)d_in[1];
  const int*   et    = (const int*)d_in[2];
  const float* Wself = (const float*)d_in[3];
  const float* bself = (const float*)d_in[4];
  const float* W1    = (const float*)d_in[5];
  const float* b1    = (const float*)d_in[6];
  const float* W2    = (const float*)d_in[7];
  const float* b2    = (const float*)d_in[8];
  float* out = (float*)d_out;

  // ws layout (310.9 MB, R7-R10 proven footprint):
  //   [0, 153.6 MB): agg bf16 [M,1536] -- hosts xb bf16 [M,512] during GEMM-1
  //   [153.6, 307.2 MB): Z bf16 [M,1536]
  //   [307.2 MB +): Wt1, Wt2, bias2
  char* ws = (char*)d_ws;
  unsigned short* xb    = (unsigned short*)ws;
  unsigned short* agg   = (unsigned short*)ws;
  unsigned short* Z     = (unsigned short*)(ws + 153600000);
  unsigned short* Wt1   = (unsigned short*)(ws + 307200000);   // 2.1 MB
  unsigned short* Wt2   = (unsigned short*)(ws + 309297152);   // 1.6 MB
  float*          bias2 = (float*)(ws + 310870016);            // 2 KB

  cast_w_kernel<<<7171, 256, 0, stream>>>(Wself, W1, W2, b2, Wt1, Wt2, bias2);
  cast_x_kernel<<<2048, 256, 0, stream>>>(x, xb, M_NODES * 512);

  // G1: Y = x @ [W_self | W1_0 | W1_1 | W1_2]  (M=50000, N=2048, K=512)
  gemm2b_kernel<16, 1, 512><<<MT256 * 16, 512, 0, stream>>>(xb, Wt1, out, Z, bself);

  hipMemsetAsync(agg, 0, (size_t)M_NODES * 1536 * sizeof(unsigned short), stream);
  scatter_all_kernel<<<E_EDGES / 4, 256, 0, stream>>>(Z, ei, et, agg);
  relu_all_kernel<<<(M_NODES * 192 + 255) / 256, 256, 0, stream>>>(Z, agg, b1);

  // G2: out += [h0|h1|h2] @ [W2_0; W2_1; W2_2] + bias2  (N=512, K=1536)
  gemm2b_kernel<4, 2, 1536><<<MT256 * 4, 512, 0, stream>>>(Z, Wt2, out, nullptr, bias2);
}